// Round 4
// baseline (1249.846 us; speedup 1.0000x reference)
//
#include <hip/hip_runtime.h>

typedef unsigned int uint;
typedef unsigned short ushort;
typedef short short8 __attribute__((ext_vector_type(8)));
typedef float floatx4 __attribute__((ext_vector_type(4)));
typedef ushort ushortx8 __attribute__((ext_vector_type(8)));
typedef ushort ushortx4 __attribute__((ext_vector_type(4)));
typedef uint uintx4 __attribute__((ext_vector_type(4)));

#define DEV static __device__ __forceinline__

#define Bsz 16
#define Cch 512
#define Tt 128
#define Nn 64
#define Hh 8
#define HD 64
#define Pp 8192        /* T*N */
#define BPOS 131072    /* B*P  */
#define C3 1536

// chunk swizzle: tiles stored as 16-byte chunks (8 bf16); row has 8 chunks
DEV int swz(int row, int c8) { return row * 8 + (c8 ^ (row & 7) ^ ((row >> 3) & 7)); }

DEV ushort f2bf(float f) {
  uint u = __float_as_uint(f);
  return (ushort)((u + 0x7FFFu + ((u >> 16) & 1u)) >> 16);  // RNE
}
DEV float bf2f(ushort h) { return __uint_as_float(((uint)h) << 16); }

// async global->LDS, 16B per lane. dst must be wave-uniform base; HW writes
// lane L at dst + L*16. Source address is per-lane (carries the inverse swizzle).
DEV void gll16(const ushort* src, ushort* dst) {
  __builtin_amdgcn_global_load_lds(
      (const __attribute__((address_space(1))) unsigned int*)src,
      (__attribute__((address_space(3))) unsigned int*)dst, 16, 0, 0);
}

// ---------------------------------------------------------------------------
// elementwise fp32 -> bf16 (weights)
// ---------------------------------------------------------------------------
__global__ __launch_bounds__(256) void k_cvt(const float* __restrict__ src,
                                             ushort* __restrict__ dst, int n) {
  int gid = blockIdx.x * 256 + threadIdx.x;
  int i8 = gid * 8;
  if (i8 < n) {
    floatx4 a = *(const floatx4*)&src[i8];
    floatx4 b = *(const floatx4*)&src[i8 + 4];
    ushortx8 o;
#pragma unroll
    for (int j = 0; j < 4; ++j) { o[j] = f2bf(a[j]); o[j + 4] = f2bf(b[j]); }
    *(ushortx8*)&dst[i8] = o;
  }
}

// ---------------------------------------------------------------------------
// x fp32 [b][c][p] -> xT bf16 [b][p][c]  (64x64 tiles via swizzled LDS)
// ---------------------------------------------------------------------------
__global__ __launch_bounds__(256) void k_transpose_x(const float* __restrict__ x,
                                                     ushort* __restrict__ xT) {
  int p0 = blockIdx.x * 64, c0 = blockIdx.y * 64, b = blockIdx.z;
  __shared__ __align__(16) ushort sm[4096];
  int tid = threadIdx.x;
  const float* xb = x + (size_t)b * Cch * Pp;
  ushort* xTb = xT + (size_t)b * Pp * Cch;
#pragma unroll
  for (int it = 0; it < 4; ++it) {
    int cc = tid + it * 256;
    int r = cc >> 4, c4 = cc & 15;
    floatx4 v = *(const floatx4*)&xb[(size_t)(c0 + r) * Pp + p0 + c4 * 4];
    ushortx4 o;
#pragma unroll
    for (int j = 0; j < 4; ++j) o[j] = f2bf(v[j]);
    *(ushortx4*)&sm[swz(r, c4 >> 1) * 8 + (c4 & 1) * 4] = o;
  }
  __syncthreads();
#pragma unroll
  for (int it = 0; it < 2; ++it) {
    int cc = tid + it * 256;
    int pl = cc >> 3, c8 = cc & 7;
    ushortx8 o;
#pragma unroll
    for (int j = 0; j < 8; ++j) {
      int c = c8 * 8 + j;
      o[j] = sm[swz(c, pl >> 3) * 8 + (pl & 7)];
    }
    *(ushortx8*)&xTb[(size_t)(p0 + pl) * Cch + c0 + c8 * 8] = o;
  }
}

// ---------------------------------------------------------------------------
// FUSED qkv-GEMM + attention. One block per (t, b); IN-PLACE xT tile -> aT.
// LDS (112 KB dynamic): A 64KB (8 k-tiles [64][8ch] swz) | pair0 24KB | pair1
// Per pair (waves 2p, 2p+1): heads p*4..p*4+3 sequentially:
//   wave wh=0: Q full + V cols 0..31 ; wh=1: K full + V cols 32..63
//   S = Q K^T (col-split), O = S V (col-split); O out via ks reuse.
// W B-fragments load straight from global (L2-resident, 1.5 MB).
// ---------------------------------------------------------------------------
__global__ __launch_bounds__(256) void k_qkv_attn(ushort* __restrict__ xaT,
                                                  const ushort* __restrict__ Wk,
                                                  const float* __restrict__ bq) {
  extern __shared__ __align__(16) ushort sm[];
  int tid = threadIdx.x, lane = tid & 63, w = tid >> 6;
  int pair = w >> 1, wh = w & 1;
  int quad = lane >> 4, col = lane & 15;
  int rr = col;
  int t = blockIdx.x, b = blockIdx.y;
  ushort* xb = xaT + ((size_t)b * Pp + (size_t)t * 64) * Cch;

  // stage A tile [64 nodes][512 k]: LDS chunk i = kt*512 + r*8 + c8
#pragma unroll
  for (int it = 0; it < 16; ++it) {
    int i = it * 256 + tid;
    int kt = i >> 9, r = (i >> 3) & 63;
    int c8 = (i & 7) ^ (r & 7) ^ ((r >> 3) & 7);
    gll16(&xb[(size_t)r * Cch + kt * 64 + c8 * 8], &sm[(it * 256 + w * 64) * 8]);
  }
  __syncthreads();

  ushort* qs = sm + 32768 + pair * 12288;  // Q tile [n][d]; later S tile [n][m]
  ushort* ks = qs + 4096;                  // K tile [m][d]; later O tile [n][d]
  ushort* vt = qs + 8192;                  // V^T tile [d][m]
  floatx4 zero4 = {0.f, 0.f, 0.f, 0.f};

  for (int hh = 0; hh < 4; ++hh) {
    int h = pair * 4 + hh;
    int rowQK = wh * 512 + h * 64;  // this wave's full-tile W rows (Q or K)
    int rowV = 1024 + h * 64 + wh * 32;

    // ---- Q (wh=0) or K (wh=1): [64 n][64 d] over K=512 ----
    floatx4 acc[4][4];
#pragma unroll
    for (int i2 = 0; i2 < 4; ++i2)
#pragma unroll
      for (int j = 0; j < 4; ++j) acc[i2][j] = zero4;
#pragma unroll
    for (int kt = 0; kt < 8; ++kt)
#pragma unroll
      for (int kk = 0; kk < 2; ++kk) {
        int g = kk * 4 + (lane >> 4);
        const ushort* wb = &Wk[(size_t)(rowQK + rr) * Cch + kt * 64 + g * 8];
        short8 af[4], bf[4];
#pragma unroll
        for (int i2 = 0; i2 < 4; ++i2)
          af[i2] = *(const short8*)&sm[kt * 4096 + swz(i2 * 16 + rr, g) * 8];
#pragma unroll
        for (int j = 0; j < 4; ++j) bf[j] = *(const short8*)&wb[(size_t)(j * 16) * Cch];
#pragma unroll
        for (int i2 = 0; i2 < 4; ++i2)
#pragma unroll
          for (int j = 0; j < 4; ++j)
            acc[i2][j] = __builtin_amdgcn_mfma_f32_16x16x32_bf16(af[i2], bf[j], acc[i2][j], 0, 0, 0);
      }
    {
      ushort* dqk = wh ? ks : qs;
#pragma unroll
      for (int j = 0; j < 4; ++j) {
        int d = j * 16 + col;
        float bj = bq[rowQK + d];
#pragma unroll
        for (int i2 = 0; i2 < 4; ++i2)
#pragma unroll
          for (int r = 0; r < 4; ++r) {
            int n = i2 * 16 + quad * 4 + r;
            dqk[swz(n, d >> 3) * 8 + (d & 7)] = f2bf(acc[i2][j][r] + bj);
          }
      }
    }

    // ---- V half: [64 n][32 d] (wh picks d-half) ----
    floatx4 accv[4][2];
#pragma unroll
    for (int i2 = 0; i2 < 4; ++i2)
#pragma unroll
      for (int j = 0; j < 2; ++j) accv[i2][j] = zero4;
#pragma unroll
    for (int kt = 0; kt < 8; ++kt)
#pragma unroll
      for (int kk = 0; kk < 2; ++kk) {
        int g = kk * 4 + (lane >> 4);
        const ushort* wb = &Wk[(size_t)(rowV + rr) * Cch + kt * 64 + g * 8];
        short8 af[4], bf[2];
#pragma unroll
        for (int i2 = 0; i2 < 4; ++i2)
          af[i2] = *(const short8*)&sm[kt * 4096 + swz(i2 * 16 + rr, g) * 8];
#pragma unroll
        for (int j = 0; j < 2; ++j) bf[j] = *(const short8*)&wb[(size_t)(j * 16) * Cch];
#pragma unroll
        for (int i2 = 0; i2 < 4; ++i2)
#pragma unroll
          for (int j = 0; j < 2; ++j)
            accv[i2][j] = __builtin_amdgcn_mfma_f32_16x16x32_bf16(af[i2], bf[j], accv[i2][j], 0, 0, 0);
      }
#pragma unroll
    for (int j = 0; j < 2; ++j) {
      int d = wh * 32 + j * 16 + col;
      float bj = bq[1024 + h * 64 + d];
#pragma unroll
      for (int i2 = 0; i2 < 4; ++i2)
#pragma unroll
        for (int r = 0; r < 4; ++r) {
          int n = i2 * 16 + quad * 4 + r;
          vt[swz(d, n >> 3) * 8 + (n & 7)] = f2bf(accv[i2][j][r] + bj);  // vT[d][m]
        }
    }
    __syncthreads();  // Q,K,V tiles ready

    // ---- S = Q K^T : this wave computes cols m in [wh*32, wh*32+32) ----
    floatx4 accs[4][2];
#pragma unroll
    for (int i2 = 0; i2 < 4; ++i2)
#pragma unroll
      for (int j = 0; j < 2; ++j) accs[i2][j] = zero4;
#pragma unroll
    for (int kk = 0; kk < 2; ++kk) {
      int g = kk * 4 + (lane >> 4);
      short8 aq[4], bk[2];
#pragma unroll
      for (int i2 = 0; i2 < 4; ++i2) aq[i2] = *(const short8*)&qs[swz(i2 * 16 + rr, g) * 8];
#pragma unroll
      for (int j = 0; j < 2; ++j) bk[j] = *(const short8*)&ks[swz(wh * 32 + j * 16 + rr, g) * 8];
#pragma unroll
      for (int i2 = 0; i2 < 4; ++i2)
#pragma unroll
        for (int j = 0; j < 2; ++j)
          accs[i2][j] = __builtin_amdgcn_mfma_f32_16x16x32_bf16(aq[i2], bk[j], accs[i2][j], 0, 0, 0);
    }
    __syncthreads();  // all qs/ks reads done before ss overwrites qs
#pragma unroll
    for (int j = 0; j < 2; ++j)
#pragma unroll
      for (int i2 = 0; i2 < 4; ++i2)
#pragma unroll
        for (int r = 0; r < 4; ++r) {
          int n = i2 * 16 + quad * 4 + r, m = wh * 32 + j * 16 + col;
          qs[swz(n, m >> 3) * 8 + (m & 7)] = f2bf(accs[i2][j][r] * 0.125f);  // ss
        }
    __syncthreads();  // ss ready

    // ---- O = S V : cols d in [wh*32, wh*32+32) ----
    floatx4 acco[4][2];
#pragma unroll
    for (int i2 = 0; i2 < 4; ++i2)
#pragma unroll
      for (int j = 0; j < 2; ++j) acco[i2][j] = zero4;
#pragma unroll
    for (int kk = 0; kk < 2; ++kk) {
      int g = kk * 4 + (lane >> 4);
      short8 as[4], bv[2];
#pragma unroll
      for (int i2 = 0; i2 < 4; ++i2) as[i2] = *(const short8*)&qs[swz(i2 * 16 + rr, g) * 8];
#pragma unroll
      for (int j = 0; j < 2; ++j) bv[j] = *(const short8*)&vt[swz(wh * 32 + j * 16 + rr, g) * 8];
#pragma unroll
      for (int i2 = 0; i2 < 4; ++i2)
#pragma unroll
        for (int j = 0; j < 2; ++j)
          acco[i2][j] = __builtin_amdgcn_mfma_f32_16x16x32_bf16(as[i2], bv[j], acco[i2][j], 0, 0, 0);
    }
#pragma unroll
    for (int j = 0; j < 2; ++j)
#pragma unroll
      for (int i2 = 0; i2 < 4; ++i2)
#pragma unroll
        for (int r = 0; r < 4; ++r) {
          int n = i2 * 16 + quad * 4 + r, d = wh * 32 + j * 16 + col;
          ks[swz(n, d >> 3) * 8 + (d & 7)] = f2bf(acco[i2][j][r]);  // O over ks
        }
    __syncthreads();  // O tile ready

    // copy out O (pair-wide, 512 chunks / 128 lanes)
#pragma unroll
    for (int it = 0; it < 4; ++it) {
      int cc = it * 128 + wh * 64 + lane;
      int n = cc >> 3, c8 = cc & 7;
      uintx4 v = *(const uintx4*)&ks[swz(n, c8) * 8];
      *(uintx4*)&xb[(size_t)n * Cch + h * 64 + c8 * 8] = v;
    }
    __syncthreads();  // ks free before next head's K write
  }
}

// ---------------------------------------------------------------------------
// GEMM2: y_bf16[n][m] = sum_k A[m][k]*W[n][k] + bias[n]   (transposed out)
// 2-deep double-buffered pipeline; fused BN partials (no atomics).
// ---------------------------------------------------------------------------
__global__ __launch_bounds__(256) void k_gemm2_t(const ushort* __restrict__ A,
                                                 const ushort* __restrict__ W,
                                                 const float* __restrict__ bias,
                                                 ushort* __restrict__ yL,
                                                 ushort* __restrict__ y0,
                                                 int K, int ldD,
                                                 size_t sAb, size_t sDb,
                                                 float* __restrict__ psum,
                                                 float* __restrict__ psq) {
  __shared__ __align__(16) ushort sm[32768];
  float* smf = (float*)sm;
  int tid = threadIdx.x;
  int lane = tid & 63, w = tid >> 6;
  int wm = (w & 1) * 64, wn = (w >> 1) * 64;
  size_t m0 = (size_t)blockIdx.y * 128;
  size_t n0 = (size_t)blockIdx.x * 128;
  const ushort* Ab = A + (size_t)blockIdx.z * sAb;
  ushort* Db = (blockIdx.z == 0) ? y0 : yL + (size_t)blockIdx.z * sDb;
  int part = blockIdx.z * 64 + blockIdx.y;

  const ushort *aS[4], *wS[4];
#pragma unroll
  for (int it = 0; it < 4; ++it) {
    int i = it * 256 + tid;
    int r = i >> 3;
    int c8 = (i & 7) ^ (r & 7) ^ ((r >> 3) & 7);
    aS[it] = &Ab[(m0 + r) * (size_t)K + c8 * 8];
    wS[it] = &W[(n0 + r) * (size_t)K + c8 * 8];
  }
  int dof = w * 512;

  floatx4 zero4 = {0.f, 0.f, 0.f, 0.f};
  floatx4 acc[4][4];
#pragma unroll
  for (int i = 0; i < 4; ++i)
#pragma unroll
    for (int j = 0; j < 4; ++j) acc[i][j] = zero4;

  const int NT = K >> 6;
#pragma unroll
  for (int it = 0; it < 4; ++it) {
    gll16(aS[it], &sm[it * 2048 + dof]);
    gll16(wS[it], &sm[8192 + it * 2048 + dof]);
  }
  __syncthreads();

  int cur = 0;
  for (int t = 0; t < NT; ++t) {
    ushort* cA = sm + (cur << 14);
    ushort* cB = cA + 8192;
    if (t + 1 < NT) {
      ushort* nA = sm + ((cur ^ 1) << 14);
      ushort* nB = nA + 8192;
      int kb = (t + 1) << 6;
#pragma unroll
      for (int it = 0; it < 4; ++it) {
        gll16(aS[it] + kb, &nA[it * 2048 + dof]);
        gll16(wS[it] + kb, &nB[it * 2048 + dof]);
      }
    }
#pragma unroll
    for (int kk = 0; kk < 2; ++kk) {
      int g = kk * 4 + (lane >> 4);
      int rr = lane & 15;
      short8 af[4], bf[4];
#pragma unroll
      for (int i = 0; i < 4; ++i) af[i] = *(const short8*)&cA[swz(wm + i * 16 + rr, g) * 8];
#pragma unroll
      for (int j = 0; j < 4; ++j) bf[j] = *(const short8*)&cB[swz(wn + j * 16 + rr, g) * 8];
#pragma unroll
      for (int i = 0; i < 4; ++i)
#pragma unroll
        for (int j = 0; j < 4; ++j)
          acc[i][j] = __builtin_amdgcn_mfma_f32_16x16x32_bf16(af[i], bf[j], acc[i][j], 0, 0, 0);
    }
    __syncthreads();
    cur ^= 1;
  }

  int quad = lane >> 4, col = lane & 15;
#pragma unroll
  for (int h = 0; h < 2; ++h) {
    __syncthreads();
    if ((w >> 1) == h) {  // waves whose wn == h*64 own this half
#pragma unroll
      for (int j = 0; j < 4; ++j) {
        int n1 = j * 16 + col;  // row within half
        float bj = bias[n0 + h * 64 + n1];
#pragma unroll
        for (int i = 0; i < 4; ++i) {
          int mb = wm + i * 16 + quad * 4;
          floatx4 v4;
#pragma unroll
          for (int r = 0; r < 4; ++r) v4[r] = acc[i][j][r] + bj;
          *(floatx4*)&smf[n1 * 128 + (mb ^ ((n1 & 7) << 2))] = v4;
        }
      }
    }
    __syncthreads();
#pragma unroll
    for (int it = 0; it < 8; ++it) {
      int cc = tid + it * 256;
      int n2 = cc >> 5, ck = cc & 31;
      floatx4 v = *(const floatx4*)&smf[n2 * 128 + ((ck * 4) ^ ((n2 & 7) << 2))];
      ushortx4 o;
#pragma unroll
      for (int r = 0; r < 4; ++r) o[r] = f2bf(v[r]);
      *(ushortx4*)&Db[(n0 + h * 64 + n2) * (size_t)ldD + m0 + ck * 4] = o;
      // BN partials from the STORED bf16 values (exactly what k_final reads)
      float s = 0.f, q = 0.f;
#pragma unroll
      for (int r = 0; r < 4; ++r) {
        float f = bf2f(o[r]);
        s += f;
        q += f * f;
      }
#pragma unroll
      for (int off = 16; off > 0; off >>= 1) {
        s += __shfl_down(s, off, 32);
        q += __shfl_down(q, off, 32);
      }
      if ((tid & 31) == 0) {
        size_t c = n0 + h * 64 + n2;
        psum[c * 1024 + part] = s;
        psq[c * 1024 + part] = q;
      }
    }
  }
}

// ---------------------------------------------------------------------------
// BN finalize (reduce scratch partials)
// ---------------------------------------------------------------------------
__global__ __launch_bounds__(256) void k_bnfin(const float* __restrict__ psum,
                                               const float* __restrict__ psq,
                                               const float* __restrict__ gamma,
                                               const float* __restrict__ beta,
                                               float* __restrict__ scaleS,
                                               float* __restrict__ shiftS) {
  int c = blockIdx.x;  // 512 blocks, one channel each
  int tid = threadIdx.x;
  floatx4 v = *(const floatx4*)&psum[(size_t)c * 1024 + tid * 4];
  floatx4 u = *(const floatx4*)&psq[(size_t)c * 1024 + tid * 4];
  float s = v[0] + v[1] + v[2] + v[3];
  float q = u[0] + u[1] + u[2] + u[3];
#pragma unroll
  for (int off = 32; off > 0; off >>= 1) {
    s += __shfl_down(s, off);
    q += __shfl_down(q, off);
  }
  __shared__ float rs[4], rq[4];
  if ((tid & 63) == 0) { rs[tid >> 6] = s; rq[tid >> 6] = q; }
  __syncthreads();
  if (tid == 0) {
    float S = rs[0] + rs[1] + rs[2] + rs[3];
    float Q = rq[0] + rq[1] + rq[2] + rq[3];
    float inv = 1.0f / (float)BPOS;
    float mean = S * inv;
    float var = Q * inv - mean * mean;
    float sc = gamma[c] * rsqrtf(var + 1e-5f);
    scaleS[c] = sc;
    shiftS[c] = beta[c] - mean * sc;
  }
}

// out[b][c][p] = y_bf16[b][c][p]*scale[c] + shift[c] + x[b][c][p]
__global__ __launch_bounds__(256) void k_final(const float* __restrict__ x,
                                               const ushort* __restrict__ y,
                                               float* __restrict__ out,
                                               const float* __restrict__ scaleS,
                                               const float* __restrict__ shiftS) {
  size_t gid = (size_t)blockIdx.x * 256 + threadIdx.x;
  size_t i8 = gid * 8;
  int c = (int)((i8 >> 13) & 511);
  float sc = scaleS[c], sh = shiftS[c];
  ushortx8 yv = *(const ushortx8*)&y[i8];
  floatx4 x0 = *(const floatx4*)&x[i8];
  floatx4 x1 = *(const floatx4*)&x[i8 + 4];
  floatx4 o0, o1;
#pragma unroll
  for (int j = 0; j < 4; ++j) {
    o0[j] = bf2f(yv[j]) * sc + sh + x0[j];
    o1[j] = bf2f(yv[j + 4]) * sc + sh + x1[j];
  }
  *(floatx4*)&out[i8] = o0;
  *(floatx4*)&out[i8 + 4] = o1;
}

// ---------------------------------------------------------------------------
extern "C" void kernel_launch(void* const* d_in, const int* in_sizes, int n_in,
                              void* d_out, int out_size, void* d_ws, size_t ws_size,
                              hipStream_t stream) {
  const float* x      = (const float*)d_in[0];
  const float* w_qkv  = (const float*)d_in[1];
  const float* b_qkv  = (const float*)d_in[2];
  const float* w_proj = (const float*)d_in[3];
  const float* b_proj = (const float*)d_in[4];
  const float* gamma  = (const float*)d_in[5];
  const float* beta   = (const float*)d_in[6];
  float* outf = (float*)d_out;  // 268,435,456 B

  // ws layout: psum 2M | psq 2M | y0 8.39M | ... | wqkvb | wprojb | st
  char* ws = (char*)d_ws;
  float*  psum   = (float*)ws;                          // 2,097,152 B
  float*  psq    = (float*)(ws + 2097152ull);           // 2,097,152 B
  ushort* y0ws   = (ushort*)(ws + 4194304ull);          // 8,388,608 B
  ushort* wqkvb  = (ushort*)(ws + 33554432ull);         // 1,572,864 B
  ushort* wprojb = (ushort*)(ws + 35127296ull);         //   524,288 B
  float*  st     = (float*)(ws + 35651584ull);          //     8 KB
  float* scaleS = st, *shiftS = st + 512;

  // d_out aliasing plan (byte-exact):
  //  Phase A (fused qkv+attn): xT slabs in UPPER half [134.2M + b*8.39M);
  //    each block reads its OWN 64 rows into LDS then overwrites them with
  //    the aT tile — fully in-place, no cross-block hazards. Lower half idle.
  //  Phase B (gemm2 z=16): reads aT (upper), writes y bf16 slabs 1..15 in
  //    LOWER half [8.39M, 134.2M); y0 -> ws.
  //  Phase C (k_final, reverse groups): {8-15} writes [134.2M,268.4M) (aT
  //    dead), reads y 8..15; {4-7} writes [67.1,134.2M) over consumed y
  //    8..15, reads y 4..7; {2-3}, {1}, {0} likewise; y0 from ws.
  ushort* xT = (ushort*)((char*)d_out + 134217728ull);
  ushort* yL = (ushort*)d_out;  // y slab b at yL + b*PC (b>=1)

  const size_t PC = (size_t)Pp * Cch;  // xT / aT / y batch stride (elements)
  const size_t CP = (size_t)Cch * Pp;  // out batch stride (floats)

  // allow 112 KB dynamic LDS (ignore result if not required on ROCm)
  static bool attrSet = false;
  if (!attrSet) {
    (void)hipFuncSetAttribute((const void*)k_qkv_attn,
                              hipFuncAttributeMaxDynamicSharedMemorySize, 114688);
    attrSet = true;
  }

  k_cvt<<<dim3(384), 256, 0, stream>>>(w_qkv, wqkvb, 3 * Cch * Cch);
  k_cvt<<<dim3(128), 256, 0, stream>>>(w_proj, wprojb, Cch * Cch);
  k_transpose_x<<<dim3(Pp / 64, Cch / 64, Bsz), 256, 0, stream>>>(x, xT);

  // fused qkv-GEMM + attention, in-place xT -> aT, single launch
  k_qkv_attn<<<dim3(Tt, Bsz), 256, 114688, stream>>>(xT, wqkvb, b_qkv);

  // gemm2: ONE launch, all 16 batches (fused BN partials from stored bf16 y)
  k_gemm2_t<<<dim3(Cch / 128, Pp / 128, 16), 256, 0, stream>>>(
      xT, wprojb, b_proj, yL, y0ws, Cch, Pp, PC, PC, psum, psq);

  k_bnfin<<<dim3(Cch), 256, 0, stream>>>(psum, psq, gamma, beta, scaleS, shiftS);

  // k_final reverse-ordered groups (see aliasing plan)
  k_final<<<dim3(8 * 2048), 256, 0, stream>>>(x + 8 * CP, yL + 8 * PC, outf + 8 * CP, scaleS, shiftS);
  k_final<<<dim3(4 * 2048), 256, 0, stream>>>(x + 4 * CP, yL + 4 * PC, outf + 4 * CP, scaleS, shiftS);
  k_final<<<dim3(2 * 2048), 256, 0, stream>>>(x + 2 * CP, yL + 2 * PC, outf + 2 * CP, scaleS, shiftS);
  k_final<<<dim3(1 * 2048), 256, 0, stream>>>(x + 1 * CP, yL + 1 * PC, outf + 1 * CP, scaleS, shiftS);
  k_final<<<dim3(1 * 2048), 256, 0, stream>>>(x, y0ws, outf, scaleS, shiftS);
}